// Round 10
// baseline (6820.828 us; speedup 1.0000x reference)
//
#include <hip/hip_runtime.h>
#include <stdint.h>

#define B_   64
#define T_   512
#define EI_  1024
#define EO_  1024
#define T_NS 128   // floor-probe steps
#define T_V  128   // versioned-probe steps

typedef __attribute__((ext_vector_type(4))) float  f32x4;
typedef __attribute__((ext_vector_type(8))) short  s16x8;
typedef __attribute__((ext_vector_type(4))) unsigned short u16x4;
typedef unsigned long long u64;

__device__ __forceinline__ unsigned short f2bf(float f) {
    union { float f; unsigned int u; } v; v.f = f;
    unsigned int r = v.u + 0x7FFFu + ((v.u >> 16) & 1u);
    return (unsigned short)(r >> 16);
}

// ---- prep: transpose weights to bf16 [N][K]; init all three H buffers; zero flags ----
__global__ void prep_kernel(const float* __restrict__ wxh, const float* __restrict__ whf,
                            const float* __restrict__ h0,
                            unsigned short* __restrict__ wxhT, unsigned short* __restrict__ whfT,
                            unsigned short* __restrict__ hbf_ns,  // [2][64][1024] (floor probe)
                            unsigned short* __restrict__ hbf6,    // [2][64][1024] (final recur)
                            unsigned int* __restrict__ flags,     // [4][64] (final recur)
                            u64* __restrict__ hvv)                // [2][64][512] granules (probe)
{
    __shared__ unsigned short Ts[64][72];
    const int bid = blockIdx.x;
    const float* src = (bid & 1) ? whf : wxh;
    unsigned short* dst = (bid & 1) ? whfT : wxhT;
    const int tile = bid >> 1;                  // 0..255
    const int k0 = (tile >> 4) * 64, n0 = (tile & 15) * 64;
    const int tid = threadIdx.x;

    #pragma unroll
    for (int it = 0; it < 4; ++it) {            // read 64x64 f32, coalesced rows
        int r  = it * 16 + (tid >> 4);
        int cq = tid & 15;
        f32x4 v = *(const f32x4*)(src + (size_t)(k0 + r) * EO_ + n0 + cq * 4);
        #pragma unroll
        for (int i = 0; i < 4; ++i) Ts[cq * 4 + i][r] = f2bf(v[i]);
    }
    __syncthreads();
    #pragma unroll
    for (int it = 0; it < 2; ++it) {            // write transposed, coalesced 16B rows
        int n = it * 32 + (tid >> 3);
        int c = tid & 7;
        s16x8 v = *(const s16x8*)(&Ts[n][c * 8]);
        *(s16x8*)(dst + (size_t)(n0 + n) * EI_ + k0 + c * 8) = v;
    }
    if (bid < 256) {
        int idx = bid * 256 + tid;              // 0..65535 == b*1024 + col
        unsigned short hb = f2bf(h0[idx]);
        hbf_ns[65536 + idx] = hb;               // parity-1 of floor probe
        hbf6[65536 + idx]   = hb;               // parity-1 of final recur
        if (idx < 32768) {
            hvv[idx] = 0xDEADBEEFull;           // parity-0: tag=lo^hi=0xDEADBEEF, never valid
            int rr = idx >> 9, gk = idx & 511;  // parity-1: tag 0 -> lo = pay, hi = pay
            unsigned int pay = (unsigned int)f2bf(h0[(size_t)rr * EO_ + gk * 2])
                             | ((unsigned int)f2bf(h0[(size_t)rr * EO_ + gk * 2 + 1]) << 16);
            hvv[32768 + idx] = (u64)pay | ((u64)pay << 32);
        }
    }
    if (bid == 0) flags[tid] = 0u;              // all 4*64 flags (replay-safe)
}

// ---- kernel 1: G = tanh(X @ wxh) into the outs region of d_out (unchanged, proven) ----
__launch_bounds__(256, 2)
__global__ void gemm_g_kernel(const float* __restrict__ X,
                              const unsigned short* __restrict__ WT,
                              float* __restrict__ out)
{
    __shared__ alignas(16) unsigned short As[128 * 72];
    __shared__ alignas(16) unsigned short Bs[128 * 72];

    const int bid = blockIdx.x;
    const int bn = bid & 7, bm = bid >> 3;
    const int m0 = bm * 128, n0 = bn * 128;
    const int tid  = threadIdx.x;
    const int lane = tid & 63, w = tid >> 6;
    const int wr = w >> 1, wc = w & 1;
    const int l15 = lane & 15, lg = lane >> 4;

    f32x4 acc[4][4] = {};

    for (int kt = 0; kt < EI_ / 64; ++kt) {
        const int k0 = kt * 64;
        #pragma unroll
        for (int p = 0; p < 8; ++p) {
            int row = p * 16 + (tid >> 4);
            int kq  = tid & 15;
            f32x4 v = *(const f32x4*)(X + (size_t)(m0 + row) * EI_ + k0 + kq * 4);
            u16x4 hv4;
            hv4[0] = f2bf(v[0]); hv4[1] = f2bf(v[1]); hv4[2] = f2bf(v[2]); hv4[3] = f2bf(v[3]);
            *(u16x4*)(&As[row * 72 + kq * 4]) = hv4;
        }
        #pragma unroll
        for (int p = 0; p < 4; ++p) {
            int n  = p * 32 + (tid >> 3);
            int kq = tid & 7;
            s16x8 v = *(const s16x8*)(WT + (size_t)(n0 + n) * EI_ + k0 + kq * 8);
            *(s16x8*)(&Bs[n * 72 + kq * 8]) = v;
        }
        __syncthreads();
        #pragma unroll
        for (int kk = 0; kk < 2; ++kk) {
            s16x8 a[4], b[4];
            #pragma unroll
            for (int mt = 0; mt < 4; ++mt)
                a[mt] = *(const s16x8*)(&As[(wr * 64 + mt * 16 + l15) * 72 + kk * 32 + lg * 8]);
            #pragma unroll
            for (int nt = 0; nt < 4; ++nt)
                b[nt] = *(const s16x8*)(&Bs[(wc * 64 + nt * 16 + l15) * 72 + kk * 32 + lg * 8]);
            #pragma unroll
            for (int mt = 0; mt < 4; ++mt)
                #pragma unroll
                for (int nt = 0; nt < 4; ++nt)
                    acc[mt][nt] = __builtin_amdgcn_mfma_f32_16x16x32_bf16(a[mt], b[nt], acc[mt][nt], 0, 0, 0);
        }
        __syncthreads();
    }
    #pragma unroll
    for (int mt = 0; mt < 4; ++mt) {
        #pragma unroll
        for (int nt = 0; nt < 4; ++nt) {
            #pragma unroll
            for (int r = 0; r < 4; ++r) {
                int row = wr * 64 + mt * 16 + lg * 4 + r;
                int col = wc * 64 + nt * 16 + l15;
                float s = acc[mt][nt][r];
                float e = __expf(2.f * s);
                out[(size_t)(m0 + row) * EO_ + n0 + col] = 1.f - 2.f / (e + 1.f);
            }
        }
    }
}

// ---- PROBE 1: mechanical floor (no sync at all), T_NS steps, writes only scratch ----
__launch_bounds__(256, 1)
__global__ void recur_ns(const float* __restrict__ h0,
                         const unsigned short* __restrict__ whfT,
                         unsigned short* hbf,
                         float* dummy,
                         const float* __restrict__ out)
{
    const int j = blockIdx.x;
    const int tid = threadIdx.x;
    const int lane = tid & 63;
    const int g = tid >> 6;
    const int l15 = lane & 15, lg = lane >> 4;

    s16x8 Wf[32];
    #pragma unroll
    for (int kk = 0; kk < 32; ++kk)
        Wf[kk] = *(const s16x8*)(whfT + (size_t)(j * 16 + l15) * EO_ + kk * 32 + lg * 8);
    #pragma unroll
    for (int kk = 0; kk < 32; ++kk)
        asm volatile("" : "+v"(Wf[kk]));

    const int row = g * 16 + l15;
    const int c0  = j * 16 + lg * 4;
    float h[4];
    {
        f32x4 v = *(const f32x4*)(h0 + (size_t)row * EO_ + c0);
        h[0] = v[0]; h[1] = v[1]; h[2] = v[2]; h[3] = v[3];
    }

    for (int t = 0; t < T_NS; ++t) {
        f32x4 gv = *(const f32x4*)(out + ((size_t)row * T_ + t) * EO_ + c0);
        asm volatile("s_waitcnt vmcnt(0)" ::: "memory");
        __builtin_amdgcn_sched_barrier(0);

        const char* aptr = (const char*)(hbf + (size_t)((t & 1) ^ 1) * 65536
                                         + (size_t)row * 1024 + lg * 8);
        f32x4 ab[32];
#define CLD(OFF) asm volatile("global_load_dwordx4 %0, %1, off offset:" #OFF " sc0 sc1" \
                              : "=&v"(ab[(OFF) / 64]) : "v"(aptr) : "memory")
        CLD(0);    CLD(64);   CLD(128);  CLD(192);  CLD(256);  CLD(320);  CLD(384);  CLD(448);
        CLD(512);  CLD(576);  CLD(640);  CLD(704);  CLD(768);  CLD(832);  CLD(896);  CLD(960);
        CLD(1024); CLD(1088); CLD(1152); CLD(1216); CLD(1280); CLD(1344); CLD(1408); CLD(1472);
        CLD(1536); CLD(1600); CLD(1664); CLD(1728); CLD(1792); CLD(1856); CLD(1920); CLD(1984);
#undef CLD
        f32x4 acc[4] = {};
        asm volatile("s_waitcnt vmcnt(0)" ::: "memory");
        __builtin_amdgcn_sched_barrier(0);
        #pragma unroll
        for (int kk = 0; kk < 32; ++kk) {
            union { f32x4 f; s16x8 s; } a_; a_.f = ab[kk];
            acc[kk & 3] = __builtin_amdgcn_mfma_f32_16x16x32_bf16(Wf[kk], a_.s, acc[kk & 3], 0, 0, 0);
        }
        f32x4 ho;
        #pragma unroll
        for (int r = 0; r < 4; ++r) {
            float s = acc[0][r] + acc[1][r] + acc[2][r] + acc[3][r];
            float fg = 1.f / (1.f + __expf(-s));
            h[r] = (1.f - fg) * h[r] + fg * gv[r];
            ho[r] = h[r];
        }
        u64 pk = (u64)f2bf(h[0]) | ((u64)f2bf(h[1]) << 16)
               | ((u64)f2bf(h[2]) << 32) | ((u64)f2bf(h[3]) << 48);
        __hip_atomic_store((u64*)(hbf + (size_t)(t & 1) * 65536 + (size_t)row * 1024 + c0),
                           pk, __ATOMIC_RELAXED, __HIP_MEMORY_SCOPE_AGENT);
        size_t oidx = ((size_t)row * T_ + t) * EO_ + c0;
        *(f32x4*)(dummy + (oidx & 16383)) = ho;
    }
    f32x4 hf; hf[0] = h[0]; hf[1] = h[1]; hf[2] = h[2]; hf[3] = h[3];
    *(f32x4*)(dummy + (((size_t)row * EO_ + c0) & 16383)) = hf;
}

// ---- PROBE 2: versioned self-certifying dataflow, FIXED: single-instruction asm loads
// with "=&v" early-clobber (dest can never alias the address pair), W in LDS (frees the
// 128 Wf VGPRs so the 256 load-dest VGPRs never spill). T_V steps, writes only scratch.
__launch_bounds__(256, 1)
__global__ void recur_v(const float* __restrict__ h0,
                        const unsigned short* __restrict__ whfT,
                        u64* hvv,                                // [2][64][512] granules
                        float* dummy,
                        const float* __restrict__ out)
{
    __shared__ alignas(16) unsigned short Ws[16 * 1032];

    const int j = blockIdx.x;
    const int tid = threadIdx.x;
    const int lane = tid & 63;
    const int g = tid >> 6;
    const int l15 = lane & 15, lg = lane >> 4;

    {   // one-time W fill (padded stride 1032)
        int c = tid >> 4, k8 = tid & 15;
        #pragma unroll
        for (int p = 0; p < 8; ++p) {
            int k = (k8 + p * 16) * 8;
            s16x8 v = *(const s16x8*)(whfT + (size_t)(j * 16 + c) * EO_ + k);
            *(s16x8*)(&Ws[c * 1032 + k]) = v;
        }
    }
    __syncthreads();

    const int row = g * 16 + l15;
    const int c0  = j * 16 + lg * 4;
    float h[4];
    {
        f32x4 v = *(const f32x4*)(h0 + (size_t)row * EO_ + c0);
        h[0] = v[0]; h[1] = v[1]; h[2] = v[2]; h[3] = v[3];
    }

    for (int t = 0; t < T_V; ++t) {
        f32x4 gv = *(const f32x4*)(out + ((size_t)row * T_ + t) * EO_ + c0);

        const unsigned int want = (unsigned int)t;
        const char* aptr = (const char*)hvv + (size_t)((t & 1) ^ 1) * 262144
                         + (size_t)row * 4096 + lg * 32;
        f32x4 ab[64];
        int passes = 0;
        bool ok;
        do {
            asm volatile("s_waitcnt vmcnt(0)" ::: "memory");
            __builtin_amdgcn_sched_barrier(0);
#define VC(I, OFF) asm volatile("global_load_dwordx4 %0, %1, off offset:" #OFF " sc0 sc1" \
                                : "=&v"(ab[I]) : "v"(aptr) : "memory")
            VC(0,0);     VC(1,16);    VC(2,128);   VC(3,144);   VC(4,256);   VC(5,272);
            VC(6,384);   VC(7,400);   VC(8,512);   VC(9,528);   VC(10,640);  VC(11,656);
            VC(12,768);  VC(13,784);  VC(14,896);  VC(15,912);  VC(16,1024); VC(17,1040);
            VC(18,1152); VC(19,1168); VC(20,1280); VC(21,1296); VC(22,1408); VC(23,1424);
            VC(24,1536); VC(25,1552); VC(26,1664); VC(27,1680); VC(28,1792); VC(29,1808);
            VC(30,1920); VC(31,1936); VC(32,2048); VC(33,2064); VC(34,2176); VC(35,2192);
            VC(36,2304); VC(37,2320); VC(38,2432); VC(39,2448); VC(40,2560); VC(41,2576);
            VC(42,2688); VC(43,2704); VC(44,2816); VC(45,2832); VC(46,2944); VC(47,2960);
            VC(48,3072); VC(49,3088); VC(50,3200); VC(51,3216); VC(52,3328); VC(53,3344);
            VC(54,3456); VC(55,3472); VC(56,3584); VC(57,3600); VC(58,3712); VC(59,3728);
            VC(60,3840); VC(61,3856); VC(62,3968); VC(63,3984);
#undef VC
            asm volatile("s_waitcnt vmcnt(0)" ::: "memory");
            __builtin_amdgcn_sched_barrier(0);
            unsigned int bad = 0;
            #pragma unroll
            for (int kk = 0; kk < 32; ++kk) {
                union { f32x4 f; unsigned int u[4]; } a_, b_;
                a_.f = ab[2 * kk]; b_.f = ab[2 * kk + 1];
                bad |= ((a_.u[0] ^ a_.u[1]) ^ want) | ((a_.u[2] ^ a_.u[3]) ^ want)
                     | ((b_.u[0] ^ b_.u[1]) ^ want) | ((b_.u[2] ^ b_.u[3]) ^ want);
            }
            ok = (bad == 0u);
        } while (__ballot(ok) != ~0ULL && ++passes < 64);

        f32x4 acc[4] = {};
        #pragma unroll
        for (int kk = 0; kk < 32; ++kk) {
            union { f32x4 f; unsigned int u[4]; } a_, b_;
            a_.f = ab[2 * kk]; b_.f = ab[2 * kk + 1];
            union { unsigned int u[4]; s16x8 s; } fr;
            fr.u[0] = a_.u[1]; fr.u[1] = a_.u[3]; fr.u[2] = b_.u[1]; fr.u[3] = b_.u[3];
            s16x8 wfrag = *(const s16x8*)(&Ws[l15 * 1032 + kk * 32 + lg * 8]);
            acc[kk & 3] = __builtin_amdgcn_mfma_f32_16x16x32_bf16(wfrag, fr.s, acc[kk & 3], 0, 0, 0);
        }

        f32x4 ho;
        #pragma unroll
        for (int r = 0; r < 4; ++r) {
            float s = acc[0][r] + acc[1][r] + acc[2][r] + acc[3][r];
            float fg = 1.f / (1.f + __expf(-s));
            h[r] = (1.f - fg) * h[r] + fg * gv[r];
            ho[r] = h[r];
        }

        unsigned int p01 = (unsigned int)f2bf(h[0]) | ((unsigned int)f2bf(h[1]) << 16);
        unsigned int p23 = (unsigned int)f2bf(h[2]) | ((unsigned int)f2bf(h[3]) << 16);
        unsigned int tg  = (unsigned int)(t + 1);
        u64 v0 = (u64)(tg ^ p01) | ((u64)p01 << 32);
        u64 v1 = (u64)(tg ^ p23) | ((u64)p23 << 32);
        u64* dst = hvv + (size_t)(t & 1) * 32768 + (size_t)row * 512 + (c0 >> 1);
        asm volatile("global_store_dwordx2 %0, %2, off sc0 sc1\n\t"
                     "global_store_dwordx2 %1, %3, off sc0 sc1"
                     :: "v"(dst), "v"(dst + 1), "v"(v0), "v"(v1) : "memory");

        size_t oidx = ((size_t)row * T_ + t) * EO_ + c0;
        *(f32x4*)(dummy + (oidx & 16383)) = ho;
    }
    f32x4 hf; hf[0] = h[0]; hf[1] = h[1]; hf[2] = h[2]; hf[3] = h[3];
    *(f32x4*)(dummy + (((size_t)row * EO_ + c0) & 16383)) = hf;
}

// ---- FINAL (PROVEN R6): wave-autonomous flag protocol, full 512 steps, writes out ----
__launch_bounds__(256, 1)
__global__ void recur_k(const float* __restrict__ h0,
                        const unsigned short* __restrict__ whfT,
                        unsigned short* hbf,                     // [2][64][1024] bf16
                        unsigned int* flags,                     // [4][64]
                        float* out)
{
    const int j = blockIdx.x;
    const int tid = threadIdx.x;
    const int lane = tid & 63;
    const int g = tid >> 6;
    const int l15 = lane & 15, lg = lane >> 4;

    s16x8 Wf[32];
    #pragma unroll
    for (int kk = 0; kk < 32; ++kk)
        Wf[kk] = *(const s16x8*)(whfT + (size_t)(j * 16 + l15) * EO_ + kk * 32 + lg * 8);
    #pragma unroll
    for (int kk = 0; kk < 32; ++kk)
        asm volatile("" : "+v"(Wf[kk]));

    const int row = g * 16 + l15;
    const int c0  = j * 16 + lg * 4;
    float h[4];
    {
        f32x4 v = *(const f32x4*)(h0 + (size_t)row * EO_ + c0);
        h[0] = v[0]; h[1] = v[1]; h[2] = v[2]; h[3] = v[3];
    }
    unsigned int* const flg = flags + g * 64;

    for (int t = 0; t < T_; ++t) {
        f32x4 gv = *(const f32x4*)(out + ((size_t)row * T_ + t) * EO_ + c0);

        const unsigned int want = (unsigned int)t;
        int spins = 0;
        for (;;) {
            unsigned int f = __hip_atomic_load(&flg[lane], __ATOMIC_RELAXED,
                                               __HIP_MEMORY_SCOPE_AGENT);
            if (__ballot(f >= want) == ~0ULL) break;
            if (++spins > (1 << 20)) break;
        }

        asm volatile("s_waitcnt vmcnt(0)" ::: "memory");
        __builtin_amdgcn_sched_barrier(0);

        const char* aptr = (const char*)(hbf + (size_t)((t & 1) ^ 1) * 65536
                                         + (size_t)row * 1024 + lg * 8);
        f32x4 ab[32];
#define CLD(OFF) asm volatile("global_load_dwordx4 %0, %1, off offset:" #OFF " sc0 sc1" \
                              : "=&v"(ab[(OFF) / 64]) : "v"(aptr) : "memory")
        CLD(0);    CLD(64);   CLD(128);  CLD(192);  CLD(256);  CLD(320);  CLD(384);  CLD(448);
        CLD(512);  CLD(576);  CLD(640);  CLD(704);  CLD(768);  CLD(832);  CLD(896);  CLD(960);
        CLD(1024); CLD(1088); CLD(1152); CLD(1216); CLD(1280); CLD(1344); CLD(1408); CLD(1472);
        CLD(1536); CLD(1600); CLD(1664); CLD(1728); CLD(1792); CLD(1856); CLD(1920); CLD(1984);
#undef CLD

        f32x4 acc[4] = {};
        asm volatile("s_waitcnt vmcnt(24)" ::: "memory");
        __builtin_amdgcn_sched_barrier(0);
        #pragma unroll
        for (int kk = 0; kk < 8; ++kk) {
            union { f32x4 f; s16x8 s; } a_; a_.f = ab[kk];
            acc[kk & 3] = __builtin_amdgcn_mfma_f32_16x16x32_bf16(Wf[kk], a_.s, acc[kk & 3], 0, 0, 0);
        }
        asm volatile("s_waitcnt vmcnt(16)" ::: "memory");
        __builtin_amdgcn_sched_barrier(0);
        #pragma unroll
        for (int kk = 8; kk < 16; ++kk) {
            union { f32x4 f; s16x8 s; } a_; a_.f = ab[kk];
            acc[kk & 3] = __builtin_amdgcn_mfma_f32_16x16x32_bf16(Wf[kk], a_.s, acc[kk & 3], 0, 0, 0);
        }
        asm volatile("s_waitcnt vmcnt(8)" ::: "memory");
        __builtin_amdgcn_sched_barrier(0);
        #pragma unroll
        for (int kk = 16; kk < 24; ++kk) {
            union { f32x4 f; s16x8 s; } a_; a_.f = ab[kk];
            acc[kk & 3] = __builtin_amdgcn_mfma_f32_16x16x32_bf16(Wf[kk], a_.s, acc[kk & 3], 0, 0, 0);
        }
        asm volatile("s_waitcnt vmcnt(0)" ::: "memory");
        __builtin_amdgcn_sched_barrier(0);
        #pragma unroll
        for (int kk = 24; kk < 32; ++kk) {
            union { f32x4 f; s16x8 s; } a_; a_.f = ab[kk];
            acc[kk & 3] = __builtin_amdgcn_mfma_f32_16x16x32_bf16(Wf[kk], a_.s, acc[kk & 3], 0, 0, 0);
        }

        f32x4 ho;
        #pragma unroll
        for (int r = 0; r < 4; ++r) {
            float s = acc[0][r] + acc[1][r] + acc[2][r] + acc[3][r];
            float fg = 1.f / (1.f + __expf(-s));
            h[r] = (1.f - fg) * h[r] + fg * gv[r];
            ho[r] = h[r];
        }

        u64 pk = (u64)f2bf(h[0]) | ((u64)f2bf(h[1]) << 16)
               | ((u64)f2bf(h[2]) << 32) | ((u64)f2bf(h[3]) << 48);
        __hip_atomic_store((u64*)(hbf + (size_t)(t & 1) * 65536 + (size_t)row * 1024 + c0),
                           pk, __ATOMIC_RELAXED, __HIP_MEMORY_SCOPE_AGENT);
        asm volatile("s_waitcnt vmcnt(0)" ::: "memory");
        if (lane == 0)
            __hip_atomic_store(&flg[j], (unsigned int)(t + 1),
                               __ATOMIC_RELAXED, __HIP_MEMORY_SCOPE_AGENT);

        *(f32x4*)(out + ((size_t)row * T_ + t) * EO_ + c0) = ho;
    }

    f32x4 hf; hf[0] = h[0]; hf[1] = h[1]; hf[2] = h[2]; hf[3] = h[3];
    *(f32x4*)(out + (size_t)B_ * T_ * EO_ + (size_t)row * EO_ + c0) = hf;
}

extern "C" void kernel_launch(void* const* d_in, const int* in_sizes, int n_in,
                              void* d_out, int out_size, void* d_ws, size_t ws_size,
                              hipStream_t stream)
{
    const float* x   = (const float*)d_in[0];
    const float* h0  = (const float*)d_in[1];
    const float* wxh = (const float*)d_in[2];
    const float* whf = (const float*)d_in[3];
    float* out = (float*)d_out;

    char* ws = (char*)d_ws;
    unsigned short* whfT   = (unsigned short*)(ws);                                   // 2MB
    unsigned short* wxhT   = (unsigned short*)(ws + (size_t)2 * 1024 * 1024);         // 2MB
    unsigned short* hbf6   = (unsigned short*)(ws + (size_t)4 * 1024 * 1024);         // 256KB
    unsigned int*   flags  = (unsigned int*)  (ws + (size_t)4 * 1024 * 1024 + 256 * 1024); // 1KB
    unsigned short* hbf_ns = (unsigned short*)(ws + (size_t)4 * 1024 * 1024 + 512 * 1024); // 256KB
    u64*            hvv    = (u64*)           (ws + (size_t)4 * 1024 * 1024 + 768 * 1024); // 512KB
    float*          dum    = (float*)         (ws + (size_t)4 * 1024 * 1024 + 1280 * 1024);// 64KB+

    prep_kernel<<<512, 256, 0, stream>>>(wxh, whf, h0, wxhT, whfT, hbf_ns, hbf6, flags, hvv);
    gemm_g_kernel<<<2048, 256, 0, stream>>>(x, wxhT, out);
    recur_ns<<<64, 256, 0, stream>>>(h0, whfT, hbf_ns, dum, out);   // floor probe
    recur_v <<<64, 256, 0, stream>>>(h0, whfT, hvv, dum, out);      // fixed versioned probe
    recur_k <<<64, 256, 0, stream>>>(h0, whfT, hbf6, flags, out);   // FINAL (proven R6)
}

// Round 12
// 4277.171 us; speedup vs baseline: 1.5947x; 1.5947x over previous
//
#include <hip/hip_runtime.h>
#include <stdint.h>

#define B_   64
#define T_   512
#define EI_  1024
#define EO_  1024

typedef __attribute__((ext_vector_type(4))) float  f32x4;
typedef __attribute__((ext_vector_type(8))) short  s16x8;
typedef __attribute__((ext_vector_type(4))) unsigned short u16x4;
typedef unsigned long long u64;

__device__ __forceinline__ unsigned short f2bf(float f) {
    union { float f; unsigned int u; } v; v.f = f;
    unsigned int r = v.u + 0x7FFFu + ((v.u >> 16) & 1u);
    return (unsigned short)(r >> 16);
}

// ---- prep: LDS tile-transpose weights to bf16 [N][K]; init H parity-1; zero flags ----
__global__ void prep_kernel(const float* __restrict__ wxh, const float* __restrict__ whf,
                            const float* __restrict__ h0,
                            unsigned short* __restrict__ wxhT, unsigned short* __restrict__ whfT,
                            unsigned short* __restrict__ hbf,   // [2][64][1024] bf16
                            unsigned int* __restrict__ flags)   // [4][64]
{
    __shared__ unsigned short Ts[64][72];
    const int bid = blockIdx.x;
    const float* src = (bid & 1) ? whf : wxh;
    unsigned short* dst = (bid & 1) ? whfT : wxhT;
    const int tile = bid >> 1;                  // 0..255
    const int k0 = (tile >> 4) * 64, n0 = (tile & 15) * 64;
    const int tid = threadIdx.x;

    #pragma unroll
    for (int it = 0; it < 4; ++it) {            // read 64x64 f32, coalesced rows
        int r  = it * 16 + (tid >> 4);
        int cq = tid & 15;
        f32x4 v = *(const f32x4*)(src + (size_t)(k0 + r) * EO_ + n0 + cq * 4);
        #pragma unroll
        for (int i = 0; i < 4; ++i) Ts[cq * 4 + i][r] = f2bf(v[i]);
    }
    __syncthreads();
    #pragma unroll
    for (int it = 0; it < 2; ++it) {            // write transposed, coalesced 16B rows
        int n = it * 32 + (tid >> 3);
        int c = tid & 7;
        s16x8 v = *(const s16x8*)(&Ts[n][c * 8]);
        *(s16x8*)(dst + (size_t)(n0 + n) * EI_ + k0 + c * 8) = v;
    }
    if (bid < 256) {                            // h0 -> bf16 parity-1 buffer
        int idx = bid * 256 + tid;              // 0..65535 == b*1024 + col
        hbf[65536 + idx] = f2bf(h0[idx]);
    }
    if (bid == 0) flags[tid] = 0u;              // zero all 4*64 flags (replay-safe)
}

// ---- kernel 1: G = tanh(X @ wxh) into the outs region of d_out. + XCD-bijective swizzle ----
__launch_bounds__(256, 2)
__global__ void gemm_g_kernel(const float* __restrict__ X,
                              const unsigned short* __restrict__ WT,
                              float* __restrict__ out)
{
    __shared__ alignas(16) unsigned short As[128 * 72];
    __shared__ alignas(16) unsigned short Bs[128 * 72];

    // 2048 blocks % 8 XCDs == 0: bijective swizzle -> each XCD gets a contiguous bm range,
    // keeping the 2MB B-matrix (WT) L2-resident per XCD.
    const int bid = (blockIdx.x & 7) * 256 + (blockIdx.x >> 3);
    const int bn = bid & 7, bm = bid >> 3;
    const int m0 = bm * 128, n0 = bn * 128;
    const int tid  = threadIdx.x;
    const int lane = tid & 63, w = tid >> 6;
    const int wr = w >> 1, wc = w & 1;
    const int l15 = lane & 15, lg = lane >> 4;

    f32x4 acc[4][4] = {};

    for (int kt = 0; kt < EI_ / 64; ++kt) {
        const int k0 = kt * 64;
        #pragma unroll
        for (int p = 0; p < 8; ++p) {
            int row = p * 16 + (tid >> 4);
            int kq  = tid & 15;
            f32x4 v = *(const f32x4*)(X + (size_t)(m0 + row) * EI_ + k0 + kq * 4);
            u16x4 hv4;
            hv4[0] = f2bf(v[0]); hv4[1] = f2bf(v[1]); hv4[2] = f2bf(v[2]); hv4[3] = f2bf(v[3]);
            *(u16x4*)(&As[row * 72 + kq * 4]) = hv4;
        }
        #pragma unroll
        for (int p = 0; p < 4; ++p) {
            int n  = p * 32 + (tid >> 3);
            int kq = tid & 7;
            s16x8 v = *(const s16x8*)(WT + (size_t)(n0 + n) * EI_ + k0 + kq * 8);
            *(s16x8*)(&Bs[n * 72 + kq * 8]) = v;
        }
        __syncthreads();
        #pragma unroll
        for (int kk = 0; kk < 2; ++kk) {
            s16x8 a[4], b[4];
            #pragma unroll
            for (int mt = 0; mt < 4; ++mt)
                a[mt] = *(const s16x8*)(&As[(wr * 64 + mt * 16 + l15) * 72 + kk * 32 + lg * 8]);
            #pragma unroll
            for (int nt = 0; nt < 4; ++nt)
                b[nt] = *(const s16x8*)(&Bs[(wc * 64 + nt * 16 + l15) * 72 + kk * 32 + lg * 8]);
            #pragma unroll
            for (int mt = 0; mt < 4; ++mt)
                #pragma unroll
                for (int nt = 0; nt < 4; ++nt)
                    acc[mt][nt] = __builtin_amdgcn_mfma_f32_16x16x32_bf16(a[mt], b[nt], acc[mt][nt], 0, 0, 0);
        }
        __syncthreads();
    }
    #pragma unroll
    for (int mt = 0; mt < 4; ++mt) {
        #pragma unroll
        for (int nt = 0; nt < 4; ++nt) {
            #pragma unroll
            for (int r = 0; r < 4; ++r) {
                int row = wr * 64 + mt * 16 + lg * 4 + r;
                int col = wc * 64 + nt * 16 + l15;
                float s = acc[mt][nt][r];
                float e = __expf(2.f * s);
                out[(size_t)(m0 + row) * EO_ + n0 + col] = 1.f - 2.f / (e + 1.f);
            }
        }
    }
}

// ---- kernel 2: recurrence (PROVEN R6 flag protocol) + split-phase wait + pipelined poll.
// 64 blocks x 4 waves, wave (j,g) owns cols [16j,16j+16) of batch group g. W pinned in
// 128 VGPRs. Chunk kk depends only on producers 0..31 (kk<16) / 32..63 (kk>=16):
//   wait flags 0..31 -> issue A-loads kk=0..15 -> wait flags 32..63 (loads drain under it)
//   -> issue kk=16..31 -> MFMA batch A immediately, chunked vmcnt for batch B.
__launch_bounds__(256, 1)
__global__ void recur_k(const float* __restrict__ h0,
                        const unsigned short* __restrict__ whfT, // whf^T bf16 [N][K]
                        unsigned short* hbf,                     // [2][64][1024] bf16
                        unsigned int* flags,                     // [4][64]
                        float* out)
{
    const int j = blockIdx.x;            // col block 0..63
    const int tid = threadIdx.x;
    const int lane = tid & 63;
    const int g = tid >> 6;              // wave = batch group 0..3
    const int l15 = lane & 15, lg = lane >> 4;

    s16x8 Wf[32];
    #pragma unroll
    for (int kk = 0; kk < 32; ++kk)
        Wf[kk] = *(const s16x8*)(whfT + (size_t)(j * 16 + l15) * EO_ + kk * 32 + lg * 8);
    #pragma unroll
    for (int kk = 0; kk < 32; ++kk)
        asm volatile("" : "+v"(Wf[kk]));

    const int row = g * 16 + l15;        // batch row this lane produces
    const int c0  = j * 16 + lg * 4;     // lane's 4 output cols
    float h[4];
    {
        f32x4 v = *(const f32x4*)(h0 + (size_t)row * EO_ + c0);
        h[0] = v[0]; h[1] = v[1]; h[2] = v[2]; h[3] = v[3];
    }
    unsigned int* const flg = flags + g * 64;

    for (int t = 0; t < T_; ++t) {
        f32x4 gv = *(const f32x4*)(out + ((size_t)row * T_ + t) * EO_ + c0);

        const unsigned int want = (unsigned int)t;
        const char* aptr = (const char*)(hbf + (size_t)((t & 1) ^ 1) * 65536
                                         + (size_t)row * 1024 + lg * 8);
        f32x4 ab[32];

        // ---- phase 1: wait for producers 0..31 (2-deep pipelined poll) ----
        {
            unsigned int fA = __hip_atomic_load(&flg[lane], __ATOMIC_RELAXED,
                                                __HIP_MEMORY_SCOPE_AGENT);
            int spins = 0;
            for (;;) {
                unsigned int fB = __hip_atomic_load(&flg[lane], __ATOMIC_RELAXED,
                                                    __HIP_MEMORY_SCOPE_AGENT);
                if (__ballot(lane >= 32 || fA >= want) == ~0ULL) break;
                fA = fB;
                if (++spins > (1 << 20)) break;
            }
        }
        __builtin_amdgcn_sched_barrier(0);
        // issue batch A: chunks kk=0..15 (cols 0..511, producers 0..31)
#define CLD(OFF) asm volatile("global_load_dwordx4 %0, %1, off offset:" #OFF " sc0 sc1" \
                              : "=&v"(ab[(OFF) / 64]) : "v"(aptr) : "memory")
        CLD(0);    CLD(64);   CLD(128);  CLD(192);  CLD(256);  CLD(320);  CLD(384);  CLD(448);
        CLD(512);  CLD(576);  CLD(640);  CLD(704);  CLD(768);  CLD(832);  CLD(896);  CLD(960);

        // ---- phase 2: wait for producers 32..63 (batch-A loads drain underneath) ----
        {
            unsigned int fA = __hip_atomic_load(&flg[lane], __ATOMIC_RELAXED,
                                                __HIP_MEMORY_SCOPE_AGENT);
            int spins = 0;
            for (;;) {
                unsigned int fB = __hip_atomic_load(&flg[lane], __ATOMIC_RELAXED,
                                                    __HIP_MEMORY_SCOPE_AGENT);
                if (__ballot(lane < 32 || fA >= want) == ~0ULL) break;
                fA = fB;
                if (++spins > (1 << 20)) break;
            }
        }
        // guarantee batch A (and gv) are in registers regardless of poll codegen
        asm volatile("s_waitcnt vmcnt(0)" ::: "memory");
        __builtin_amdgcn_sched_barrier(0);
        // issue batch B: chunks kk=16..31 (cols 512..1023, producers 32..63)
        CLD(1024); CLD(1088); CLD(1152); CLD(1216); CLD(1280); CLD(1344); CLD(1408); CLD(1472);
        CLD(1536); CLD(1600); CLD(1664); CLD(1728); CLD(1792); CLD(1856); CLD(1920); CLD(1984);
#undef CLD

        f32x4 acc[4] = {};
        // batch A is ready: MFMA immediately while batch B returns
        #pragma unroll
        for (int kk = 0; kk < 16; ++kk) {
            union { f32x4 f; s16x8 s; } a_; a_.f = ab[kk];
            acc[kk & 3] = __builtin_amdgcn_mfma_f32_16x16x32_bf16(Wf[kk], a_.s, acc[kk & 3], 0, 0, 0);
        }
        asm volatile("s_waitcnt vmcnt(8)" ::: "memory");
        __builtin_amdgcn_sched_barrier(0);
        #pragma unroll
        for (int kk = 16; kk < 24; ++kk) {
            union { f32x4 f; s16x8 s; } a_; a_.f = ab[kk];
            acc[kk & 3] = __builtin_amdgcn_mfma_f32_16x16x32_bf16(Wf[kk], a_.s, acc[kk & 3], 0, 0, 0);
        }
        asm volatile("s_waitcnt vmcnt(0)" ::: "memory");
        __builtin_amdgcn_sched_barrier(0);
        #pragma unroll
        for (int kk = 24; kk < 32; ++kk) {
            union { f32x4 f; s16x8 s; } a_; a_.f = ab[kk];
            acc[kk & 3] = __builtin_amdgcn_mfma_f32_16x16x32_bf16(Wf[kk], a_.s, acc[kk & 3], 0, 0, 0);
        }

        f32x4 ho;
        #pragma unroll
        for (int r = 0; r < 4; ++r) {
            float s = acc[0][r] + acc[1][r] + acc[2][r] + acc[3][r];
            float fg = 1.f / (1.f + __expf(-s));
            h[r] = (1.f - fg) * h[r] + fg * gv[r];
            ho[r] = h[r];
        }

        // critical path: packed bf16 H-store -> drain -> flag; out-store afterwards
        u64 pk = (u64)f2bf(h[0]) | ((u64)f2bf(h[1]) << 16)
               | ((u64)f2bf(h[2]) << 32) | ((u64)f2bf(h[3]) << 48);
        __hip_atomic_store((u64*)(hbf + (size_t)(t & 1) * 65536 + (size_t)row * 1024 + c0),
                           pk, __ATOMIC_RELAXED, __HIP_MEMORY_SCOPE_AGENT);
        asm volatile("s_waitcnt vmcnt(0)" ::: "memory");   // H-store visible before flag
        if (lane == 0)
            __hip_atomic_store(&flg[j], (unsigned int)(t + 1),
                               __ATOMIC_RELAXED, __HIP_MEMORY_SCOPE_AGENT);

        *(f32x4*)(out + ((size_t)row * T_ + t) * EO_ + c0) = ho;   // h_t -> outs (plain)
    }

    f32x4 hf; hf[0] = h[0]; hf[1] = h[1]; hf[2] = h[2]; hf[3] = h[3];
    *(f32x4*)(out + (size_t)B_ * T_ * EO_ + (size_t)row * EO_ + c0) = hf;
}

extern "C" void kernel_launch(void* const* d_in, const int* in_sizes, int n_in,
                              void* d_out, int out_size, void* d_ws, size_t ws_size,
                              hipStream_t stream)
{
    const float* x   = (const float*)d_in[0];
    const float* h0  = (const float*)d_in[1];
    const float* wxh = (const float*)d_in[2];
    const float* whf = (const float*)d_in[3];
    float* out = (float*)d_out;

    char* ws = (char*)d_ws;
    unsigned short* whfT  = (unsigned short*)(ws);                               // 2MB
    unsigned short* wxhT  = (unsigned short*)(ws + (size_t)2 * 1024 * 1024);     // 2MB
    unsigned short* hbf   = (unsigned short*)(ws + (size_t)4 * 1024 * 1024);     // 256KB
    unsigned int*   flags = (unsigned int*)  (ws + (size_t)4 * 1024 * 1024 + 256 * 1024);

    prep_kernel<<<512, 256, 0, stream>>>(wxh, whf, h0, wxhT, whfT, hbf, flags);
    gemm_g_kernel<<<2048, 256, 0, stream>>>(x, wxhT, out);
    recur_k<<<64, 256, 0, stream>>>(h0, whfT, hbf, flags, out);
}